// Round 7
// baseline (224.125 us; speedup 1.0000x reference)
//
#include <hip/hip_runtime.h>

// ---------------------------------------------------------------------------
// self_transformer: q=xW1^T+b1, k=xW2^T+b2, v=xW3^T+b3,
//                   attn=softmax((k q^T)/sqrt(D)), out=attn@v
// N=4096, D=1024. R14 = R12 schedule (best known: 42.5us/gemm) with ONE
// change: MFMA shape 16x16x32 -> 32x32x16 (m119: +15% ceiling, 2495 vs
// 2176 TF; halves MFMA instruction count: 8/phase/wave vs 16). R13's
// read-ahead + fused-rsum are REVERTED (regressed E-gemm 42.5->50.5).
//   Per-wave 128x64 output = 4 m-frags x 2 n-frags of 32x32.
//   A/B lane addressing: row = lane&31, k-granule = ks*2 + (lane>>5)
//   (8 contiguous bf16 per granule) -- the 32-lane analog of the proven
//   16x16x32 addressing (row=lane&15, granule=lane>>4).
//   C/D layout: col=lane&31, row=(v&3)+8*(v>>2)+4*(lane>>5) [m74/m101].
//   LDS layout UNCHANGED: half [128 rows][8 granules of 8 shorts], slot
//   s of row r holds global granule s^(r&7). Bank check for the new read:
//   addr = row*128B + slot*16B -> start-bank = slot*4; lanes cover all 8
//   slot values evenly (granule ^ (l32&7)) -> 8 lanes per start-bank =
//   bandwidth-optimal, 0 conflicts (same math as the 16x16 version that
//   measured SQ_LDS_BANK_CONFLICT == 0 across R7-R13).
//   Schedule (verbatim R12): 8 phases / 2 K-tiles per iteration; reads
//   in-phase (ph1: B0+A0 12 reads, ph2: B1 4, ph3: A1 8, ph4: 0; mirror
//   ph5-8); 1 stage (2 gld_lds) per phase, rotation ph1:t+1.A1,
//   ph2:t+2.A0, ph3:t+2.B0, ph4:t+2.B1, ph5:t+2.A1, ph6:t+3.A0,
//   ph7:t+3.B0, ph8:t+3.B1; vmcnt(6) only at ph4/ph8 (publishes tile t+1
//   / t+2: outstanding = 3 newest stages -> all older retired); 1 barrier
//   per phase (post-MFMA); last iteration peeled, vmcnt(0) only there.
//   WAR: every stage's slot had its last read >=1 barrier earlier.
// ---------------------------------------------------------------------------

typedef short bf16x8 __attribute__((ext_vector_type(8)));   // 8 bf16 = 4 VGPRs
typedef float f32x16 __attribute__((ext_vector_type(16)));  // 32x32 C/D frag

struct FalseT { static constexpr bool value = false; };
struct TrueT  { static constexpr bool value = true;  };

__device__ __forceinline__ short f2bf(float f) {
    unsigned u = __builtin_bit_cast(unsigned, f);
    u += 0x7FFFu + ((u >> 16) & 1u);   // round-to-nearest-even
    return (short)(u >> 16);
}
__device__ __forceinline__ float bf2f(short s) {
    return __builtin_bit_cast(float, (unsigned)((unsigned short)s) << 16);
}

__device__ __forceinline__ void gld_lds16(const short* g, short* l) {
    __builtin_amdgcn_global_load_lds(
        (const __attribute__((address_space(1))) void*)g,
        (__attribute__((address_space(3))) void*)l, 16, 0, 0);
}

#define WAITV(n) asm volatile("s_waitcnt vmcnt(" #n ")" ::: "memory")
#define BAR()    __builtin_amdgcn_s_barrier()

// ---------------------------------------------------------------------------
// 256x256 BT GEMM, BK=64, 512 threads = 8 waves (2M x 4N), per-wave 128x64.
// C[a][b] = scale * sum_i A[a*lda+i] * B[b*ldb+i].
// CMODE: 0 = bf16 + bias; 2 = bf16 exp(); 3 = bf16 at split-K z*zstride.
// Requires K % 128 == 0.
// ---------------------------------------------------------------------------
template<int CMODE>
__global__ __launch_bounds__(512)
void gemm256(const short* __restrict__ A, int lda,
             const short* __restrict__ B, int ldb,
             const float* __restrict__ bias,
             short* __restrict__ Cout, int ldc, float scale,
             int K, size_t zstride)
{
    __shared__ __align__(16) short As[2][2][128 * 64];  // [parity][mq-half]
    __shared__ __align__(16) short Bs[2][2][128 * 64];  // [parity][nq-half]

    const int tid  = threadIdx.x;
    const int lane = tid & 63;
    const int wave = tid >> 6;           // 0..7
    const int wr   = wave >> 2;          // 0..1
    const int wc   = wave & 3;           // 0..3
    const int l32  = lane & 31;
    const int khalf = lane >> 5;         // 0/1: k-granule within a K=16 frag
    const size_t bm0 = (size_t)blockIdx.y * 256;
    const size_t bn0 = (size_t)blockIdx.x * 256;
    const int koff = blockIdx.z * K;

    f32x16 acc[4][2] = {};               // [m-frag mq*2+f][nq]

    // staging decode: stage call writes 16 rows (wave*16..+15) of one half;
    // lane l -> row +8*i+(l>>3), LDS slot (l&7), global granule (l&7)^(l>>3)
    const int srow  = lane >> 3;
    const int sgran = (lane & 7) ^ srow;
    const short* Ag0 = A + (bm0 + wave * 16 + srow) * (size_t)lda + koff + sgran * 8;
    const short* Ag1 = Ag0 + (size_t)128 * lda;
    const short* Bg0 = B + (bn0 + wave * 16 + srow) * (size_t)ldb + koff + sgran * 8;
    const short* Bg1 = Bg0 + (size_t)128 * ldb;

    // fragment reads: row = base + l32 (row&7 == l32&7), granule ks*2+khalf
    // -> slot = (ks*2+khalf) ^ (l32&7), element offset = slot*8.
    const int sx   = l32 & 7;
    const int rdA0 = (wr * 64 + l32) * 64;
    const int rdB0 = (wc * 32 + l32) * 64;

    auto stage = [&](short* half, const short* g, int ld, int kt) {
#pragma unroll
        for (int i = 0; i < 2; ++i)
            gld_lds16(g + (size_t)(i * 8) * ld + kt,
                      half + (wave * 16 + i * 8) * 64);
    };

    bf16x8 af[2][4], bfr0[4], bfr1[4];   // af[f][ks], b[ks]

    auto ldA = [&](const short* Ah) {    // 8 reads: current mq's A-frags
#pragma unroll
        for (int f = 0; f < 2; ++f)
#pragma unroll
            for (int ks = 0; ks < 4; ++ks)
                af[f][ks] = *(const bf16x8*)(
                    Ah + rdA0 + f * 2048 + (((ks * 2 + khalf) ^ sx) << 3));
    };
    auto ldB = [&](bf16x8 (&bx)[4], const short* Bh) {   // 4 reads
#pragma unroll
        for (int ks = 0; ks < 4; ++ks)
            bx[ks] = *(const bf16x8*)(
                Bh + rdB0 + (((ks * 2 + khalf) ^ sx) << 3));
    };
    // one quadrant x K=64: 8 MFMA (2 f-chains x 4 ks, interleaved)
    auto mm = [&](int mq, int nq, bf16x8 (&bx)[4]) {
        __builtin_amdgcn_s_setprio(1);
#pragma unroll
        for (int ks = 0; ks < 4; ++ks)
#pragma unroll
            for (int f = 0; f < 2; ++f)
                acc[mq * 2 + f][nq] = __builtin_amdgcn_mfma_f32_32x32x16_bf16(
                    af[f][ks], bx[ks], acc[mq * 2 + f][nq], 0, 0, 0);
        __builtin_amdgcn_s_setprio(0);
    };

    // prologue: tile0 all 4 halves (8 loads, retired by vmcnt(6)), then
    // tile1 {A0,B0,B1} (6 loads, stay in flight). tile1.A1 staged at ph1.
    stage(&As[0][0][0], Ag0, lda, 0);
    stage(&Bs[0][0][0], Bg0, ldb, 0);
    stage(&Bs[0][1][0], Bg1, ldb, 0);
    stage(&As[0][1][0], Ag1, lda, 0);
    stage(&As[1][0][0], Ag0, lda, 64);
    stage(&Bs[1][0][0], Bg0, ldb, 64);
    stage(&Bs[1][1][0], Bg1, ldb, 64);
    WAITV(6);
    BAR();
    __builtin_amdgcn_sched_barrier(0);

    int kt = 0;
    auto iterbody = [&](auto LASTC) {
        constexpr bool LAST = decltype(LASTC)::value;
        // ==== parity 0 : tile t ====
        // ph1 (Q00): reads B0 (4) + A-mq0 (8)
        ldB(bfr0, &Bs[0][0][0]);
        ldA(&As[0][0][0]);
        stage(&As[1][1][0], Ag1, lda, kt + 64);        // t+1.A1
        mm(0, 0, bfr0);
        BAR();
        // ph2 (Q01): reads B1 (4)
        ldB(bfr1, &Bs[0][1][0]);
        if constexpr (!LAST) stage(&As[0][0][0], Ag0, lda, kt + 128);  // t+2.A0
        mm(0, 1, bfr1);
        BAR();
        // ph3 (Q11): reads A-mq1 (8)
        ldA(&As[0][1][0]);
        if constexpr (!LAST) stage(&Bs[0][0][0], Bg0, ldb, kt + 128);  // t+2.B0
        mm(1, 1, bfr1);
        BAR();
        // ph4 (Q10): no reads; publish tile t+1
        if constexpr (!LAST) stage(&Bs[0][1][0], Bg1, ldb, kt + 128);  // t+2.B1
        mm(1, 0, bfr0);
        if constexpr (LAST) { WAITV(0); } else { WAITV(6); }
        __builtin_amdgcn_sched_barrier(0);
        BAR();
        // ==== parity 1 : tile t+1 ====
        // ph5 (Q00)
        ldB(bfr0, &Bs[1][0][0]);
        ldA(&As[1][0][0]);
        if constexpr (!LAST) stage(&As[0][1][0], Ag1, lda, kt + 128);  // t+2.A1
        mm(0, 0, bfr0);
        BAR();
        // ph6 (Q01)
        ldB(bfr1, &Bs[1][1][0]);
        if constexpr (!LAST) stage(&As[1][0][0], Ag0, lda, kt + 192);  // t+3.A0
        mm(0, 1, bfr1);
        BAR();
        // ph7 (Q11)
        ldA(&As[1][1][0]);
        if constexpr (!LAST) stage(&Bs[1][0][0], Bg0, ldb, kt + 192);  // t+3.B0
        mm(1, 1, bfr1);
        BAR();
        // ph8 (Q10): no reads; publish tile t+2
        if constexpr (!LAST) stage(&Bs[1][1][0], Bg1, ldb, kt + 192);  // t+3.B1
        mm(1, 0, bfr0);
        if constexpr (!LAST) {
            WAITV(6);
            __builtin_amdgcn_sched_barrier(0);
        }
        BAR();
    };

    const int nfull = (K >> 7) - 1;      // K % 128 == 0
    for (int i = 0; i < nfull; ++i) {
        iterbody(FalseT{});
        kt += 128;
    }
    iterbody(TrueT{});

    // epilogue: 32x32 C/D layout col=lane&31, row=(v&3)+8*(v>>2)+4*khalf
    short* Cs = Cout + ((CMODE == 3) ? (size_t)blockIdx.z * zstride : 0);
#pragma unroll
    for (int mf = 0; mf < 4; ++mf) {
        const int mq = mf >> 1, f = mf & 1;
#pragma unroll
        for (int nq = 0; nq < 2; ++nq) {
            const size_t col = bn0 + nq * 128 + wc * 32 + l32;
            const float bc = (CMODE == 0) ? bias[col] : 0.0f;
#pragma unroll
            for (int v = 0; v < 16; ++v) {
                const size_t row = bm0 + mq * 128 + wr * 64 + f * 32 +
                                   (v & 3) + ((v >> 2) << 3) + khalf * 4;
                float val = acc[mf][nq][v] * scale + bc;
                if (CMODE == 2) val = __expf(val);
                Cs[row * (size_t)ldc + col] = f2bf(val);
            }
        }
    }
}

// 64x64 LDS-tiled transpose: vt[d][n] = qkv[n*3072 + 2048 + d]
__global__ __launch_bounds__(256)
void transpose_v(const short* __restrict__ qkv, short* __restrict__ vt)
{
    __shared__ short sh[64][72];   // +8 pad
    const int n0 = blockIdx.x * 64, d0 = blockIdx.y * 64;
    const int t = threadIdx.x;
    const int r = t >> 2, c = (t & 3) << 4;

    const short* src = qkv + (size_t)(n0 + r) * 3072 + 2048 + d0 + c;
    *(int4*)(&sh[r][c])     = *(const int4*)(src);
    *(int4*)(&sh[r][c + 8]) = *(const int4*)(src + 8);
    __syncthreads();

    short tmp[16];
#pragma unroll
    for (int j = 0; j < 16; j++) tmp[j] = sh[c + j][r];
    short* dst = vt + (size_t)(d0 + r) * 4096 + n0 + c;
    *(int4*)(dst)     = *(const int4*)(tmp);
    *(int4*)(dst + 8) = *(const int4*)(tmp + 8);
}

// One block per output row n: rsum = sum(E[n,:]); out[n,:] =
// (sum_z partial_z[n,:]) / rsum. Partials are bf16, 4 splits of 4096x1024.
__global__ __launch_bounds__(256)
void reduce4div(const short* __restrict__ E, const short* __restrict__ outp,
                float* __restrict__ out)
{
    const int row = blockIdx.x;
    const int t = threadIdx.x;
    const int wave = t >> 6, lane = t & 63;

    // row-sum of E[row][4096], 16 elems/thread
    const short* e = E + (size_t)row * 4096 + (t << 4);
    short sh[16];
    *(int4*)(sh)     = *(const int4*)(e);
    *(int4*)(sh + 8) = *(const int4*)(e + 8);
    float s = 0.0f;
#pragma unroll
    for (int i = 0; i < 16; i++) s += bf2f(sh[i]);
#pragma unroll
    for (int off = 32; off; off >>= 1) s += __shfl_down(s, off);
    __shared__ float red[4];
    if (lane == 0) red[wave] = s;
    __syncthreads();
    const float inv = 1.0f / (red[0] + red[1] + red[2] + red[3]);

    // sum 4 bf16 partial rows, 4 cols/thread
    const size_t base = (size_t)row * 1024 + (t << 2);
    float a[4] = {0.0f, 0.0f, 0.0f, 0.0f};
#pragma unroll
    for (int z = 0; z < 4; z++) {
        short4 p = *(const short4*)(outp + z * (size_t)4096 * 1024 + base);
        a[0] += bf2f(p.x); a[1] += bf2f(p.y);
        a[2] += bf2f(p.z); a[3] += bf2f(p.w);
    }
    float4 o;
    o.x = a[0] * inv; o.y = a[1] * inv; o.z = a[2] * inv; o.w = a[3] * inv;
    *(float4*)(out + base) = o;
}

// single prep: x->xb (1M float4), W1|W2|W3 -> Wb (3x256K float4), bias cat
// Wb sub-matrix offsets are in SHORT ELEMENTS (1048576 elems per W).
__global__ __launch_bounds__(256)
void prep(const float* __restrict__ x, const float* __restrict__ W1,
          const float* __restrict__ W2, const float* __restrict__ W3,
          const float* __restrict__ b1, const float* __restrict__ b2,
          const float* __restrict__ b3,
          short* __restrict__ xb, short* __restrict__ Wb,
          float* __restrict__ bcat)
{
    const int i = blockIdx.x * 256 + threadIdx.x;
    const int NX = 1048576;           // 4096*1024/4
    const int NW = 262144;            // 1024*1024/4
    if (i < NX + 3 * NW) {
        const float* src; short* dst; int j;
        if (i < NX)               { src = x;  dst = xb; j = i; }
        else if (i < NX + NW)     { src = W1; dst = Wb; j = i - NX; }
        else if (i < NX + 2 * NW) { src = W2; dst = Wb + 1048576; j = i - NX - NW; }
        else                      { src = W3; dst = Wb + 2097152; j = i - NX - 2 * NW; }
        const float4 f = ((const float4*)src)[j];
        short4 o;
        o.x = f2bf(f.x); o.y = f2bf(f.y); o.z = f2bf(f.z); o.w = f2bf(f.w);
        *(short4*)(dst + (j << 2)) = o;
    } else {
        const int j = i - (NX + 3 * NW);
        if (j < 3072)
            bcat[j] = (j < 1024) ? b1[j] : (j < 2048 ? b2[j - 1024] : b3[j - 2048]);
    }
}

extern "C" void kernel_launch(void* const* d_in, const int* in_sizes, int n_in,
                              void* d_out, int out_size, void* d_ws, size_t ws_size,
                              hipStream_t stream)
{
    const float* x  = (const float*)d_in[0];
    const float* W1 = (const float*)d_in[1];
    const float* b1 = (const float*)d_in[2];
    const float* W2 = (const float*)d_in[3];
    const float* b2 = (const float*)d_in[4];
    const float* W3 = (const float*)d_in[5];
    const float* b3 = (const float*)d_in[6];
    float* out = (float*)d_out;

    const int N = 4096, D = 1024;

    // workspace (peak 79 MB):
    //   vt   [0, 8M)            live: transpose .. out-gemm
    //   E    [8M, 40M)          live: S-gemm .. reduce
    //   xb   [40M, 48M)  \
    //   Wb   [48M, 54M)   }     dead after S-gemm
    //   bcat [54M, +12K)  }
    //   qkv  [54M+16K, ~78M)   /
    //   outp [40M, 72M)         bf16 partials, overlays dead region
    char* wsb = (char*)d_ws;
    short* vt   = (short*)wsb;                               // 1024x4096 bf16
    short* E    = (short*)(wsb + (size_t)8  * 1024 * 1024);  // 4096x4096 bf16
    short* xb   = (short*)(wsb + (size_t)40 * 1024 * 1024);  // 4096x1024 bf16
    short* Wb   = (short*)(wsb + (size_t)48 * 1024 * 1024);  // 3072x1024 bf16
    float* bcat = (float*)(wsb + (size_t)54 * 1024 * 1024);  // 3072 fp32
    short* qkv  = (short*)(wsb + (size_t)54 * 1024 * 1024 + 16384); // 4096x3072
    short* outp = (short*)(wsb + (size_t)40 * 1024 * 1024);  // 4x 4096x1024 bf16

    // 1) prep: casts + bias concat (one launch)
    prep<<<(1048576 + 3 * 262144 + 3072 + 255) / 256, 256, 0, stream>>>(
        x, W1, W2, W3, b1, b2, b3, xb, Wb, bcat);

    // 2) qkv = x @ [W1;W2;W3]^T + bias  (256x256, grid (12,16)=192)
    dim3 gqkv(3 * D / 256, N / 256);
    gemm256<0><<<gqkv, 512, 0, stream>>>(xb, D, Wb, D, bcat,
                                         qkv, 3 * D, 1.0f, D, 0);

    // 3) vt[d][n] = v[n][d]   grid (64,16)=1024 blocks
    dim3 gt(N / 64, D / 64);
    transpose_v<<<gt, 256, 0, stream>>>(qkv, vt);

    // 4) E = exp((k q^T)/32) bf16  (256x256, grid (16,16)=256)
    dim3 gs(N / 256, N / 256);
    gemm256<2><<<gs, 512, 0, stream>>>(qkv + D, 3 * D, qkv, 3 * D,
                                       nullptr, E, N, 0.03125f, D, 0);

    // 5) out partials = E @ vt^T, split-K=4, bf16 (grid (4,16,4)=256)
    dim3 go(D / 256, N / 256, 4);
    gemm256<3><<<go, 512, 0, stream>>>(E, N, vt, N, nullptr,
                                       outp, D, 1.0f, N / 4,
                                       (size_t)N * D);

    // 6) out = (sum_z partial_z) / rowsum(E)
    reduce4div<<<N, 256, 0, stream>>>(E, outp, out);
}

// Round 8
// 214.793 us; speedup vs baseline: 1.0434x; 1.0434x over previous
//
#include <hip/hip_runtime.h>

// ---------------------------------------------------------------------------
// self_transformer: q=xW1^T+b1, k=xW2^T+b2, v=xW3^T+b3,
//                   attn=softmax((k q^T)/sqrt(D)), out=attn@v
// N=4096, D=1024. All matmuls via mfma_f32_16x16x32_bf16, fp32 accum.
// R15 = R12 base (best measured: 42.5us/gemm, 212.5 total; 16x16x32 MFMA,
//       0 bank conflicts) + ONE change: E row-sum fused into the E-gemm
//       epilogue (per-quad shfl_xor reduce + fp32 atomicAdd into rsum[4096],
//       zeroed by prep). reduce4div no longer re-reads the 32 MB E matrix.
//       R14's 32x32x16 shape is REVERTED (introduced 3.1M bank conflicts,
//       45.5us/gemm). R13's read-ahead is REVERTED (regressed E-gemm +8us).
//   Schedule (verbatim R12): 8 phases / 2 K-tiles per iteration; reads
//   in-phase, consume order (B-ks0, A-ks0, B-ks1, A-ks1) with compiler
//   per-use lgkmcnt; 1 stage (2 gld_lds) per phase, rotation ph1:t+1.A1,
//   ph2:t+2.A0, ph3:t+2.B0, ph4:t+2.B1, ph5:t+2.A1, ph6:t+3.A0,
//   ph7:t+3.B0, ph8:t+3.B1; vmcnt(6) only at ph4/ph8 (publishes tile t+1 /
//   t+2); 1 barrier per phase (post-MFMA); last iteration peeled (vmcnt(0)
//   only there). WAR: every stage's slot had its last read >=1 barrier
//   earlier. LDS half [128 rows][8 granules of 8 shorts], slot s of row r
//   holds global granule s^(r&7); read slot (ks*4+quad)^(l16&7) ->
//   0 conflicts (measured R7-R13).
//   rsum numerics: sums the SAME rounded-bf16 exp values reduce4div
//   previously summed (order-only fp32 diff; R13 measured identical absmax).
// ---------------------------------------------------------------------------

typedef short bf16x8 __attribute__((ext_vector_type(8)));  // 8 bf16 = 4 VGPRs
typedef float f32x4  __attribute__((ext_vector_type(4)));

struct FalseT { static constexpr bool value = false; };
struct TrueT  { static constexpr bool value = true;  };

__device__ __forceinline__ short f2bf(float f) {
    unsigned u = __builtin_bit_cast(unsigned, f);
    u += 0x7FFFu + ((u >> 16) & 1u);   // round-to-nearest-even
    return (short)(u >> 16);
}
__device__ __forceinline__ float bf2f(short s) {
    return __builtin_bit_cast(float, (unsigned)((unsigned short)s) << 16);
}

__device__ __forceinline__ void gld_lds16(const short* g, short* l) {
    __builtin_amdgcn_global_load_lds(
        (const __attribute__((address_space(1))) void*)g,
        (__attribute__((address_space(3))) void*)l, 16, 0, 0);
}

#define WAITV(n) asm volatile("s_waitcnt vmcnt(" #n ")" ::: "memory")
#define BAR()    __builtin_amdgcn_s_barrier()

// ---------------------------------------------------------------------------
// 256x256 BT GEMM, BK=64, 512 threads = 8 waves (2M x 4N), per-wave 128x64
// output spread across quadrant halves. C[a][b] = scale * sum A[a,i]*B[b,i].
// CMODE: 0 = bf16 + bias; 2 = bf16 exp() + fused row-sum atomics into rsum;
//        3 = bf16 at split-K z*zstride.  Requires K % 128 == 0.
// ---------------------------------------------------------------------------
template<int CMODE>
__global__ __launch_bounds__(512)
void gemm256(const short* __restrict__ A, int lda,
             const short* __restrict__ B, int ldb,
             const float* __restrict__ bias,
             short* __restrict__ Cout, int ldc, float scale,
             int K, size_t zstride, float* __restrict__ rsum)
{
    __shared__ __align__(16) short As[2][2][128 * 64];  // [parity][mq-half]
    __shared__ __align__(16) short Bs[2][2][128 * 64];  // [parity][nq-half]

    const int tid  = threadIdx.x;
    const int lane = tid & 63;
    const int wave = tid >> 6;           // 0..7
    const int wr   = wave >> 2;          // 0..1
    const int wc   = wave & 3;           // 0..3
    const int quad = lane >> 4;
    const int l16  = lane & 15;
    const size_t bm0 = (size_t)blockIdx.y * 256;
    const size_t bn0 = (size_t)blockIdx.x * 256;
    const int koff = blockIdx.z * K;

    f32x4 acc[8][4] = {};

    // staging decode: stage call writes 16 rows (wave*16..+15) of one half;
    // lane l -> row +8*i+(l>>3), LDS slot (l&7), global granule (l&7)^(l>>3)
    const int srow  = lane >> 3;
    const int sgran = (lane & 7) ^ srow;
    const short* Ag0 = A + (bm0 + wave * 16 + srow) * (size_t)lda + koff + sgran * 8;
    const short* Ag1 = Ag0 + (size_t)128 * lda;
    const short* Bg0 = B + (bn0 + wave * 16 + srow) * (size_t)ldb + koff + sgran * 8;
    const short* Bg1 = Bg0 + (size_t)128 * ldb;

    // fragment read offsets within a [128][64] half
    const int s0   = ((quad ^ (l16 & 7)) << 3);         // ks=0 slot
    const int s1   = (((4 + quad) ^ (l16 & 7)) << 3);   // ks=1 slot
    const int rdA0 = (wr * 64 + l16) * 64;
    const int rdB0 = (wc * 32 + l16) * 64;

    auto stage = [&](short* half, const short* g, int ld, int kt) {
#pragma unroll
        for (int i = 0; i < 2; ++i)
            gld_lds16(g + (size_t)(i * 8) * ld + kt,
                      half + (wave * 16 + i * 8) * 64);
    };

    bf16x8 af[4][2], bfr0[2][2], bfr1[2][2];

    auto ldA = [&](const short* Ah, int ks, int soff) {
#pragma unroll
        for (int m4 = 0; m4 < 4; ++m4)
            af[m4][ks] = *(const bf16x8*)(Ah + rdA0 + m4 * 1024 + soff);
    };
    auto ldB = [&](bf16x8 (&bx)[2][2], const short* Bh, int ks, int soff) {
#pragma unroll
        for (int n2 = 0; n2 < 2; ++n2)
            bx[n2][ks] = *(const bf16x8*)(Bh + rdB0 + n2 * 1024 + soff);
    };
    auto mmks = [&](int mq, int nq, bf16x8 (&bx)[2][2], int ks) {
#pragma unroll
        for (int m4 = 0; m4 < 4; ++m4)
#pragma unroll
            for (int n2 = 0; n2 < 2; ++n2)
                acc[mq * 4 + m4][nq * 2 + n2] =
                    __builtin_amdgcn_mfma_f32_16x16x32_bf16(
                        af[m4][ks], bx[n2][ks],
                        acc[mq * 4 + m4][nq * 2 + n2], 0, 0, 0);
    };

    // prologue: tile0 all 4 halves (8 loads, retired by vmcnt(6)), then
    // tile1 {A0,B0,B1} (6 loads, stay in flight). tile1.A1 staged at ph1.
    stage(&As[0][0][0], Ag0, lda, 0);
    stage(&Bs[0][0][0], Bg0, ldb, 0);
    stage(&Bs[0][1][0], Bg1, ldb, 0);
    stage(&As[0][1][0], Ag1, lda, 0);
    stage(&As[1][0][0], Ag0, lda, 64);
    stage(&Bs[1][0][0], Bg0, ldb, 64);
    stage(&Bs[1][1][0], Bg1, ldb, 64);
    WAITV(6);
    BAR();
    __builtin_amdgcn_sched_barrier(0);

    int kt = 0;
    auto iterbody = [&](auto LASTC) {
        constexpr bool LAST = decltype(LASTC)::value;
        // ---- ph1: tile t, quadrant (0,0) ----
        ldB(bfr0, &Bs[0][0][0], 0, s0);
        ldA(&As[0][0][0], 0, s0);
        ldB(bfr0, &Bs[0][0][0], 1, s1);
        ldA(&As[0][0][0], 1, s1);
        stage(&As[1][1][0], Ag1, lda, kt + 64);        // t+1.A1
        __builtin_amdgcn_s_setprio(1);
        mmks(0, 0, bfr0, 0); mmks(0, 0, bfr0, 1);
        __builtin_amdgcn_s_setprio(0);
        BAR();
        // ---- ph2: (0,1) ----
        ldB(bfr1, &Bs[0][1][0], 0, s0);
        ldB(bfr1, &Bs[0][1][0], 1, s1);
        if constexpr (!LAST) stage(&As[0][0][0], Ag0, lda, kt + 128);  // t+2.A0
        __builtin_amdgcn_s_setprio(1);
        mmks(0, 1, bfr1, 0); mmks(0, 1, bfr1, 1);
        __builtin_amdgcn_s_setprio(0);
        BAR();
        // ---- ph3: (1,1) ----
        ldA(&As[0][1][0], 0, s0);
        ldA(&As[0][1][0], 1, s1);
        if constexpr (!LAST) stage(&Bs[0][0][0], Bg0, ldb, kt + 128);  // t+2.B0
        __builtin_amdgcn_s_setprio(1);
        mmks(1, 1, bfr1, 0); mmks(1, 1, bfr1, 1);
        __builtin_amdgcn_s_setprio(0);
        BAR();
        // ---- ph4: (1,0) — register-only MFMA, publish tile t+1 ----
        if constexpr (!LAST) stage(&Bs[0][1][0], Bg1, ldb, kt + 128);  // t+2.B1
        __builtin_amdgcn_s_setprio(1);
        mmks(1, 0, bfr0, 0); mmks(1, 0, bfr0, 1);
        __builtin_amdgcn_s_setprio(0);
        if constexpr (LAST) { WAITV(0); } else { WAITV(6); }
        __builtin_amdgcn_sched_barrier(0);
        BAR();
        // ---- ph5: tile t+1, quadrant (0,0) ----
        ldB(bfr0, &Bs[1][0][0], 0, s0);
        ldA(&As[1][0][0], 0, s0);
        ldB(bfr0, &Bs[1][0][0], 1, s1);
        ldA(&As[1][0][0], 1, s1);
        if constexpr (!LAST) stage(&As[0][1][0], Ag1, lda, kt + 128);  // t+2.A1
        __builtin_amdgcn_s_setprio(1);
        mmks(0, 0, bfr0, 0); mmks(0, 0, bfr0, 1);
        __builtin_amdgcn_s_setprio(0);
        BAR();
        // ---- ph6: (0,1) ----
        ldB(bfr1, &Bs[1][1][0], 0, s0);
        ldB(bfr1, &Bs[1][1][0], 1, s1);
        if constexpr (!LAST) stage(&As[1][0][0], Ag0, lda, kt + 192);  // t+3.A0
        __builtin_amdgcn_s_setprio(1);
        mmks(0, 1, bfr1, 0); mmks(0, 1, bfr1, 1);
        __builtin_amdgcn_s_setprio(0);
        BAR();
        // ---- ph7: (1,1) ----
        ldA(&As[1][1][0], 0, s0);
        ldA(&As[1][1][0], 1, s1);
        if constexpr (!LAST) stage(&Bs[1][0][0], Bg0, ldb, kt + 192);  // t+3.B0
        __builtin_amdgcn_s_setprio(1);
        mmks(1, 1, bfr1, 0); mmks(1, 1, bfr1, 1);
        __builtin_amdgcn_s_setprio(0);
        BAR();
        // ---- ph8: (1,0) — register-only MFMA, publish tile t+2 ----
        if constexpr (!LAST) stage(&Bs[1][1][0], Bg1, ldb, kt + 192);  // t+3.B1
        __builtin_amdgcn_s_setprio(1);
        mmks(1, 0, bfr0, 0); mmks(1, 0, bfr0, 1);
        __builtin_amdgcn_s_setprio(0);
        if constexpr (!LAST) {
            WAITV(6);
            __builtin_amdgcn_sched_barrier(0);
        }
        BAR();
    };

    const int nfull = (K >> 7) - 1;      // K % 128 == 0
    for (int i = 0; i < nfull; ++i) {
        iterbody(FalseT{});
        kt += 128;
    }
    iterbody(TrueT{});

    // epilogue: C/D layout col=lane&15, row=quad*4+reg; wave rows/cols are
    // split across the two quadrant halves. CMODE==2 additionally reduces
    // each row's 4 per-thread exp values across nt, then across the 16
    // lanes of the quad (shfl_xor 1/2/4/8 stay within the quad), and
    // atomicAdds into rsum[row] (same rounded-bf16 values the old
    // reduce4div summed; fp32 order-only difference).
    short* Cs = Cout + ((CMODE == 3) ? (size_t)blockIdx.z * zstride : 0);
#pragma unroll
    for (int mt = 0; mt < 8; ++mt) {
        const int mq = mt >> 2, m4 = mt & 3;
#pragma unroll
        for (int r = 0; r < 4; ++r) {
            const size_t row = bm0 + mq * 128 + wr * 64 + m4 * 16 + quad * 4 + r;
            float s = 0.0f;
#pragma unroll
            for (int nt = 0; nt < 4; ++nt) {
                const int nq = nt >> 1, n2 = nt & 1;
                const size_t col = bn0 + nq * 128 + wc * 32 + n2 * 16 + l16;
                float v = acc[mt][nt][r] * scale +
                          ((CMODE == 0) ? bias[col] : 0.0f);
                if (CMODE == 2) v = __expf(v);
                const short h = f2bf(v);
                Cs[row * (size_t)ldc + col] = h;
                if (CMODE == 2) s += bf2f(h);
            }
            if (CMODE == 2) {
                s += __shfl_xor(s, 1);
                s += __shfl_xor(s, 2);
                s += __shfl_xor(s, 4);
                s += __shfl_xor(s, 8);
                if (l16 == 0) atomicAdd(&rsum[row], s);
            }
        }
    }
}

// 64x64 LDS-tiled transpose: vt[d][n] = qkv[n*3072 + 2048 + d]
__global__ __launch_bounds__(256)
void transpose_v(const short* __restrict__ qkv, short* __restrict__ vt)
{
    __shared__ short sh[64][72];   // +8 pad
    const int n0 = blockIdx.x * 64, d0 = blockIdx.y * 64;
    const int t = threadIdx.x;
    const int r = t >> 2, c = (t & 3) << 4;

    const short* src = qkv + (size_t)(n0 + r) * 3072 + 2048 + d0 + c;
    *(int4*)(&sh[r][c])     = *(const int4*)(src);
    *(int4*)(&sh[r][c + 8]) = *(const int4*)(src + 8);
    __syncthreads();

    short tmp[16];
#pragma unroll
    for (int j = 0; j < 16; j++) tmp[j] = sh[c + j][r];
    short* dst = vt + (size_t)(d0 + r) * 4096 + n0 + c;
    *(int4*)(dst)     = *(const int4*)(tmp);
    *(int4*)(dst + 8) = *(const int4*)(tmp + 8);
}

// One block per output row n: out[n,:] = (sum_z partial_z[n,:]) / rsum[n].
// rsum was accumulated by the E-gemm epilogue (fp32 atomics).
__global__ __launch_bounds__(256)
void reduce4div(const float* __restrict__ rsum, const short* __restrict__ outp,
                float* __restrict__ out)
{
    const int row = blockIdx.x;
    const int t = threadIdx.x;
    const float inv = 1.0f / rsum[row];

    // sum 4 bf16 partial rows, 4 cols/thread
    const size_t base = (size_t)row * 1024 + (t << 2);
    float a[4] = {0.0f, 0.0f, 0.0f, 0.0f};
#pragma unroll
    for (int z = 0; z < 4; z++) {
        short4 p = *(const short4*)(outp + z * (size_t)4096 * 1024 + base);
        a[0] += bf2f(p.x); a[1] += bf2f(p.y);
        a[2] += bf2f(p.z); a[3] += bf2f(p.w);
    }
    float4 o;
    o.x = a[0] * inv; o.y = a[1] * inv; o.z = a[2] * inv; o.w = a[3] * inv;
    *(float4*)(out + base) = o;
}

// single prep: x->xb (1M float4), W1|W2|W3 -> Wb (3x256K float4), bias cat,
// rsum[4096] zero-init. Wb sub-matrix offsets in SHORT ELEMENTS.
__global__ __launch_bounds__(256)
void prep(const float* __restrict__ x, const float* __restrict__ W1,
          const float* __restrict__ W2, const float* __restrict__ W3,
          const float* __restrict__ b1, const float* __restrict__ b2,
          const float* __restrict__ b3,
          short* __restrict__ xb, short* __restrict__ Wb,
          float* __restrict__ bcat, float* __restrict__ rsum)
{
    const int i = blockIdx.x * 256 + threadIdx.x;
    const int NX = 1048576;           // 4096*1024/4
    const int NW = 262144;            // 1024*1024/4
    if (i < NX + 3 * NW) {
        const float* src; short* dst; int j;
        if (i < NX)               { src = x;  dst = xb; j = i; }
        else if (i < NX + NW)     { src = W1; dst = Wb; j = i - NX; }
        else if (i < NX + 2 * NW) { src = W2; dst = Wb + 1048576; j = i - NX - NW; }
        else                      { src = W3; dst = Wb + 2097152; j = i - NX - 2 * NW; }
        const float4 f = ((const float4*)src)[j];
        short4 o;
        o.x = f2bf(f.x); o.y = f2bf(f.y); o.z = f2bf(f.z); o.w = f2bf(f.w);
        *(short4*)(dst + (j << 2)) = o;
    } else {
        const int j = i - (NX + 3 * NW);
        if (j < 3072)
            bcat[j] = (j < 1024) ? b1[j] : (j < 2048 ? b2[j - 1024] : b3[j - 2048]);
        else if (j < 3072 + 4096)
            rsum[j - 3072] = 0.0f;
    }
}

extern "C" void kernel_launch(void* const* d_in, const int* in_sizes, int n_in,
                              void* d_out, int out_size, void* d_ws, size_t ws_size,
                              hipStream_t stream)
{
    const float* x  = (const float*)d_in[0];
    const float* W1 = (const float*)d_in[1];
    const float* b1 = (const float*)d_in[2];
    const float* W2 = (const float*)d_in[3];
    const float* b2 = (const float*)d_in[4];
    const float* W3 = (const float*)d_in[5];
    const float* b3 = (const float*)d_in[6];
    float* out = (float*)d_out;

    const int N = 4096, D = 1024;

    // workspace (peak ~79 MB + 16K):
    //   vt   [0, 8M)            live: transpose .. out-gemm
    //   E    [8M, 40M)          live: S-gemm .. out-gemm
    //   xb   [40M, 48M)  \
    //   Wb   [48M, 54M)   }     dead after S-gemm
    //   bcat [54M, +12K)  }
    //   qkv  [54M+16K, ~78M)   /
    //   outp [40M, 72M)         bf16 partials, overlays dead region
    //   rsum [79M, +16K)        fp32, live: prep .. reduce
    char* wsb = (char*)d_ws;
    short* vt   = (short*)wsb;                               // 1024x4096 bf16
    short* E    = (short*)(wsb + (size_t)8  * 1024 * 1024);  // 4096x4096 bf16
    short* xb   = (short*)(wsb + (size_t)40 * 1024 * 1024);  // 4096x1024 bf16
    short* Wb   = (short*)(wsb + (size_t)48 * 1024 * 1024);  // 3072x1024 bf16
    float* bcat = (float*)(wsb + (size_t)54 * 1024 * 1024);  // 3072 fp32
    short* qkv  = (short*)(wsb + (size_t)54 * 1024 * 1024 + 16384); // 4096x3072
    short* outp = (short*)(wsb + (size_t)40 * 1024 * 1024);  // 4x 4096x1024 bf16
    float* rsum = (float*)(wsb + (size_t)79 * 1024 * 1024);  // 4096 fp32

    // 1) prep: casts + bias concat + rsum zero (one launch)
    prep<<<(1048576 + 3 * 262144 + 3072 + 4096 + 255) / 256, 256, 0, stream>>>(
        x, W1, W2, W3, b1, b2, b3, xb, Wb, bcat, rsum);

    // 2) qkv = x @ [W1;W2;W3]^T + bias  (256x256, grid (12,16)=192)
    dim3 gqkv(3 * D / 256, N / 256);
    gemm256<0><<<gqkv, 512, 0, stream>>>(xb, D, Wb, D, bcat,
                                         qkv, 3 * D, 1.0f, D, 0, nullptr);

    // 3) vt[d][n] = v[n][d]   grid (64,16)=1024 blocks
    dim3 gt(N / 64, D / 64);
    transpose_v<<<gt, 256, 0, stream>>>(qkv, vt);

    // 4) E = exp((k q^T)/32) bf16 + fused row-sums (256x256, grid 16x16)
    dim3 gs(N / 256, N / 256);
    gemm256<2><<<gs, 512, 0, stream>>>(qkv + D, 3 * D, qkv, 3 * D,
                                       nullptr, E, N, 0.03125f, D, 0, rsum);

    // 5) out partials = E @ vt^T, split-K=4, bf16 (grid (4,16,4)=256)
    dim3 go(D / 256, N / 256, 4);
    gemm256<3><<<go, 512, 0, stream>>>(E, N, vt, N, nullptr,
                                       outp, D, 1.0f, N / 4,
                                       (size_t)N * D, nullptr);

    // 6) out = (sum_z partial_z) / rsum
    reduce4div<<<N, 256, 0, stream>>>(rsum, outp, out);
}